// Round 8
// baseline (877.793 us; speedup 1.0000x reference)
//
#include <hip/hip_runtime.h>

// ---------------------------------------------------------------------------
// GATv2 (2 layers), bucketed LDS-accumulator formulation.
// Bucket = dst >> 6 (64 nodes/bucket, 782 buckets). Scatter = block-level
// counting sort (LDS hist -> scan -> one global atomic per bucket per block
// -> staged bucket-grouped write-out; coalesced full lines).
// gather1: ONE block per bucket. xr rows + acc[64][64] + den[64][8] live in
// LDS; 16 waves take disjoint 64-entry windows, readlane the (uniform) entry,
// gather xl[src] (8-deep unrolled for latency hiding), accumulate with
// ds_add_f32 LDS atomics. Each entry processed exactly once (the previous
// ballot-filter design scanned each entry 64x and serialized on the
// ballot->readlane->load chain). gather2: fully edge-parallel, one entry per
// thread, LDS num/den per node.
// 8-lane head reduction via DPP; exp2 with log2e prefolded. Softmax without
// max-subtraction (scores O(10), exp fp32-safe; shift-invariant). Self-loops
// handled analytically at accumulator init, never stored.
// ---------------------------------------------------------------------------

#define NEG_SLOPE 0.2f
#define LOG2E 1.4426950408889634f
#define CB_SHIFT 6
#define CB_MASK 63
#define CAP_C 3072     // mean 2048/bucket, sigma~45 -> 22-sigma headroom
#define CHUNK 8192     // edges per scatter block (8 per thread)
#define CNT_STRIDE 32  // one counter per 128B

#if __has_builtin(__builtin_amdgcn_exp2f)
#define EXP2(x) __builtin_amdgcn_exp2f(x)
#else
#define EXP2(x) __expf((x)*0.6931471805599453f)
#endif

// 8-lane-group sum via DPP: quad_perm swap1, swap2, row_half_mirror.
__device__ __forceinline__ float dpp_add_xor1(float x) {
  int v = __builtin_amdgcn_update_dpp(0, __float_as_int(x), 0xB1, 0xF, 0xF, true);
  return x + __int_as_float(v);
}
__device__ __forceinline__ float dpp_add_xor2(float x) {
  int v = __builtin_amdgcn_update_dpp(0, __float_as_int(x), 0x4E, 0xF, 0xF, true);
  return x + __int_as_float(v);
}
__device__ __forceinline__ float dpp_add_half_mirror(float x) {
  int v = __builtin_amdgcn_update_dpp(0, __float_as_int(x), 0x141, 0xF, 0xF, true);
  return x + __int_as_float(v);
}
__device__ __forceinline__ float head8_sum(float x) {
  return dpp_add_half_mirror(dpp_add_xor2(dpp_add_xor1(x)));
}

// out[n][j] = sum_k x[n][k] * W[k][j].  One wave per node per iteration;
// lane j holds W[:,j] in 128 VGPRs; x-row broadcast via readlane.
__global__ __launch_bounds__(256) void gemm_reg(
    const float* __restrict__ x, const float* __restrict__ W,
    float* __restrict__ out, int N, int nwaves) {
  int wid = blockIdx.x * 4 + (threadIdx.x >> 6);
  int j = threadIdx.x & 63;
  float Wcol[128];
#pragma unroll
  for (int k = 0; k < 128; ++k) Wcol[k] = W[k * 64 + j];  // coalesced, L2-hot
  for (int n = wid; n < N; n += nwaves) {
    const float2 xv2 = *(const float2*)&x[(size_t)n * 128 + 2 * j];
    float xa = xv2.x, xb = xv2.y;  // lane l holds x[n][2l], x[n][2l+1]
    float acc0 = 0.f, acc1 = 0.f;
#pragma unroll
    for (int k = 0; k < 128; k += 2) {
      unsigned b0 = __builtin_amdgcn_readlane(__float_as_uint(xa), k >> 1);
      unsigned b1 = __builtin_amdgcn_readlane(__float_as_uint(xb), k >> 1);
      acc0 = fmaf(__uint_as_float(b0), Wcol[k], acc0);
      acc1 = fmaf(__uint_as_float(b1), Wcol[k + 1], acc1);
    }
    out[(size_t)n * 64 + j] = acc0 + acc1;
  }
}

// Block-level counting-sort scatter: CHUNK edges -> bucket-grouped global buf.
__global__ __launch_bounds__(1024) void bucket_scatter(
    const int* __restrict__ ei, int E0, int* __restrict__ bcnt,
    int* __restrict__ buf) {
  __shared__ int hist[1024];          // per-bucket counts (782 used)
  __shared__ int sc[1024];            // scan / later: exclusive seg start
  __shared__ int gofs[1024];          // bucket_base + global_rank - seg_start
  __shared__ unsigned stage[CHUNK];   // (bucket<<22) | entry, bucket-grouped
  int tid = threadIdx.x;
  int base = blockIdx.x * CHUNK;
  hist[tid] = 0;
  __syncthreads();
  int bb[8], pp[8], ent[8];
#pragma unroll
  for (int r = 0; r < 8; ++r) {
    int e = base + r * 1024 + tid;
    if (e < E0) {
      int s = ei[e], d = ei[E0 + e];
      int b = d >> CB_SHIFT;
      bb[r] = b;
      ent[r] = (s << CB_SHIFT) | (d & CB_MASK);
      pp[r] = atomicAdd(&hist[b], 1);  // LDS atomic: rank within (block,bucket)
    } else {
      bb[r] = -1;
    }
  }
  __syncthreads();
  int v = hist[tid];
  sc[tid] = v;
  __syncthreads();
  for (int off = 1; off < 1024; off <<= 1) {  // Hillis-Steele inclusive scan
    int u = (tid >= off) ? sc[tid - off] : 0;
    __syncthreads();
    sc[tid] += u;
    __syncthreads();
  }
  int total = sc[1023];
  int excl = sc[tid] - v;
  int gb = 0;
  if (v > 0) gb = atomicAdd(&bcnt[tid * CNT_STRIDE], v);  // reserve range
  __syncthreads();
  sc[tid] = excl;                        // seg start of bucket `tid` in stage[]
  gofs[tid] = tid * CAP_C + gb - excl;   // write addr = gofs[bucket] + stage_idx
  __syncthreads();
#pragma unroll
  for (int r = 0; r < 8; ++r) {
    if (bb[r] >= 0)
      stage[sc[bb[r]] + pp[r]] = ((unsigned)bb[r] << 22) | (unsigned)ent[r];
  }
  __syncthreads();
  for (int i = tid; i < total; i += 1024) {
    unsigned pe = stage[i];
    int b = pe >> 22;
    int addr = gofs[b] + i;
    if (addr < b * CAP_C + CAP_C)  // statistical overflow guard (22 sigma)
      buf[addr] = (int)(pe & 0x3FFFFFu);
  }
}

// Fused layer-1 gather: one block per 64-node bucket; LDS accumulators.
__global__ __launch_bounds__(1024) void gather1(
    const int* __restrict__ bcnt, const int* __restrict__ buf,
    const float* __restrict__ xl, const float* __restrict__ xr,
    const float* __restrict__ att, const float* __restrict__ b1,
    const float* __restrict__ W2l, const float* __restrict__ W2r,
    float* __restrict__ hl, float* __restrict__ hr, int N) {
  __shared__ float xrs[64][64];   // xr rows of the bucket's nodes
  __shared__ float accs[64][64];  // sum of w*xl per node
  __shared__ float dens[64][8];   // sum of w per node per head
  int bucket = blockIdx.x;
  int tid = threadIdx.x;
  int w = tid >> 6, lane = tid & 63;
  int cnt = min(bcnt[bucket * CNT_STRIDE], CAP_C);
  int nbase = bucket << CB_SHIFT;
  float av = att[lane] * LOG2E;  // exp(p) == exp2(p*log2e)
  // stage xr rows (coalesced); zero rows past N (never referenced by edges)
  for (int r = w; r < 64; r += 16) {
    int nn = nbase + r;
    xrs[r][lane] = (nn < N) ? xr[(size_t)nn * 64 + lane] : 0.f;
  }
  // self-loop init: wave w inits nodes w*4 .. w*4+3
#pragma unroll
  for (int j = 0; j < 4; ++j) {
    int r = w * 4 + j;
    int nn = nbase + r;
    if (nn < N) {
      float a = xl[(size_t)nn * 64 + lane];
      float bvv = xr[(size_t)nn * 64 + lane];
      float t = a + bvv;
      t = fmaxf(t, NEG_SLOPE * t);
      float wgt = EXP2(head8_sum(t * av));
      accs[r][lane] = wgt * a;
      if ((lane & 7) == 0) dens[r][lane >> 3] = wgt;
    } else {
      accs[r][lane] = 0.f;
      if ((lane & 7) == 0) dens[r][lane >> 3] = 1.f;
    }
  }
  __syncthreads();
  const int* __restrict__ bseg = buf + (size_t)bucket * CAP_C;
  for (int start = w * 64; start < cnt; start += 1024) {
    int rem = cnt - start;
    int e = (start + lane < cnt) ? bseg[start + lane] : 0;
    if (rem >= 64) {
#pragma unroll 8
      for (int i = 0; i < 64; ++i) {
        int ev = __builtin_amdgcn_readlane(e, i);
        int s = ev >> CB_SHIFT, dl = ev & CB_MASK;
        float a = xl[((size_t)s << 6) + lane];
        float t = a + xrs[dl][lane];
        t = fmaxf(t, NEG_SLOPE * t);
        float wgt = EXP2(head8_sum(t * av));
        atomicAdd(&accs[dl][lane], wgt * a);
        if ((lane & 7) == 0) atomicAdd(&dens[dl][lane >> 3], wgt);
      }
    } else {
      for (int i = 0; i < rem; ++i) {
        int ev = __builtin_amdgcn_readlane(e, i);
        int s = ev >> CB_SHIFT, dl = ev & CB_MASK;
        float a = xl[((size_t)s << 6) + lane];
        float t = a + xrs[dl][lane];
        t = fmaxf(t, NEG_SLOPE * t);
        float wgt = EXP2(head8_sum(t * av));
        atomicAdd(&accs[dl][lane], wgt * a);
        if ((lane & 7) == 0) atomicAdd(&dens[dl][lane >> 3], wgt);
      }
    }
  }
  __syncthreads();
  // finalize: normalize, +b1, ELU, project to layer-2 scalars hl, hr
#pragma unroll
  for (int j = 0; j < 4; ++j) {
    int r = w * 4 + j;
    int nn = nbase + r;
    if (nn >= N) continue;
    float v = accs[r][lane] / dens[r][lane >> 3] + b1[lane];
    float h = v > 0.f ? v : (__expf(v) - 1.f);  // ELU(alpha=1)
    float pl = h * W2l[lane];
    float pr = h * W2r[lane];
#pragma unroll
    for (int off = 1; off < 64; off <<= 1) {
      pl += __shfl_xor(pl, off);
      pr += __shfl_xor(pr, off);
    }
    if (lane == 0) { hl[nn] = pl; hr[nn] = pr; }
  }
}

// Layer-2 gather: one block per bucket, fully edge-parallel (one entry per
// thread); LDS num/den per node. hl is 200KB -> L2-resident random gathers.
__global__ __launch_bounds__(1024) void gather2(
    const int* __restrict__ bcnt, const int* __restrict__ buf,
    const float* __restrict__ hl, const float* __restrict__ hr,
    const float* __restrict__ att2, const float* __restrict__ b2,
    float* __restrict__ out, int N) {
  __shared__ float hrs[64];
  __shared__ float num[64];
  __shared__ float den[64];
  int bucket = blockIdx.x;
  int tid = threadIdx.x;
  int cnt = min(bcnt[bucket * CNT_STRIDE], CAP_C);
  int nbase = bucket << CB_SHIFT;
  float a2 = att2[0] * LOG2E;
  if (tid < 64) {  // stage hr + self-loop init
    int nn = nbase + tid;
    if (nn < N) {
      float hld = hl[nn], hrd = hr[nn];
      hrs[tid] = hrd;
      float t = hld + hrd;
      t = fmaxf(t, NEG_SLOPE * t);
      float wgt = EXP2(t * a2);
      num[tid] = wgt * hld;
      den[tid] = wgt;
    } else {
      hrs[tid] = 0.f; num[tid] = 0.f; den[tid] = 1.f;
    }
  }
  __syncthreads();
  const int* __restrict__ bseg = buf + (size_t)bucket * CAP_C;
  for (int i = tid; i < cnt; i += 1024) {
    int e = bseg[i];
    int s = e >> CB_SHIFT, dl = e & CB_MASK;
    float hls = hl[s];
    float t = hls + hrs[dl];
    t = fmaxf(t, NEG_SLOPE * t);
    float wgt = EXP2(t * a2);
    atomicAdd(&num[dl], wgt * hls);
    atomicAdd(&den[dl], wgt);
  }
  __syncthreads();
  if (tid < 64) {
    int nn = nbase + tid;
    if (nn < N) out[nn] = num[tid] / den[tid] + b2[0];
  }
}

extern "C" void kernel_launch(void* const* d_in, const int* in_sizes, int n_in,
                              void* d_out, int out_size, void* d_ws, size_t ws_size,
                              hipStream_t stream) {
  const float* x    = (const float*)d_in[0];
  const int*   ei   = (const int*)d_in[1];
  const float* W1l  = (const float*)d_in[2];
  const float* W1r  = (const float*)d_in[3];
  const float* att1 = (const float*)d_in[4];
  const float* b1   = (const float*)d_in[5];
  const float* W2l  = (const float*)d_in[6];
  const float* W2r  = (const float*)d_in[7];
  const float* att2 = (const float*)d_in[8];
  const float* b2   = (const float*)d_in[9];
  float* out = (float*)d_out;

  const int N  = in_sizes[0] / 128;          // 50000
  const int E0 = in_sizes[1] / 2;            // 1600000
  const int NB = (N + CB_MASK) >> CB_SHIFT;  // 782 buckets of 64 nodes

  // workspace layout
  float* ws  = (float*)d_ws;
  size_t NF  = (size_t)N * 64;
  float* xl  = ws;            // N*64
  float* xr  = xl + NF;       // N*64
  float* hl  = xr + NF;       // N
  float* hr  = hl + N;        // N
  int* bcnt  = (int*)(hr + N);                  // NB*CNT_STRIDE (zeroed)
  int* buf   = bcnt + (size_t)NB * CNT_STRIDE;  // NB*CAP_C

  hipMemsetAsync(bcnt, 0, (size_t)NB * CNT_STRIDE * sizeof(int), stream);

  const int GEMM_BLOCKS = 512;  // 2048 waves
  const int GEMM_WAVES  = GEMM_BLOCKS * 4;
  gemm_reg<<<GEMM_BLOCKS, 256, 0, stream>>>(x, W1l, xl, N, GEMM_WAVES);
  gemm_reg<<<GEMM_BLOCKS, 256, 0, stream>>>(x, W1r, xr, N, GEMM_WAVES);
  bucket_scatter<<<(E0 + CHUNK - 1) / CHUNK, 1024, 0, stream>>>(ei, E0, bcnt, buf);
  gather1<<<NB, 1024, 0, stream>>>(bcnt, buf, xl, xr, att1, b1, W2l, W2r,
                                   hl, hr, N);
  gather2<<<NB, 1024, 0, stream>>>(bcnt, buf, hl, hr, att2, b2, out, N);
}

// Round 9
// 876.304 us; speedup vs baseline: 1.0017x; 1.0017x over previous
//
#include <hip/hip_runtime.h>

// ---------------------------------------------------------------------------
// GATv2 (2 layers), bucketed LDS-accumulator formulation.
// Bucket = dst >> 6 (64 nodes/bucket, 782 buckets). Scatter = block-level
// counting sort (LDS hist -> scan -> one global atomic per bucket per block
// -> staged bucket-grouped write-out; coalesced full lines).
// gather1: ONE block per bucket. xr rows + acc[64][64] + den[64][8] live in
// LDS; 16 waves take disjoint 64-entry windows, readlane the (uniform) entry,
// gather xl[src], accumulate with NATIVE ds_add_f32 via unsafeAtomicAdd.
// (R8 lesson: plain atomicAdd(float*) on LDS compiles to a CAS retry loop --
//  ~2 LDS round-trips per op serialized per wave -> 788us. unsafeAtomicAdd
//  emits ds_add_f32.)
// gather2: fully edge-parallel, one entry per thread, LDS num/den per node.
// 8-lane head reduction via DPP; exp2 with log2e prefolded. Softmax without
// max-subtraction (scores O(10), exp fp32-safe; shift-invariant). Self-loops
// handled analytically at accumulator init, never stored.
// ---------------------------------------------------------------------------

#define NEG_SLOPE 0.2f
#define LOG2E 1.4426950408889634f
#define CB_SHIFT 6
#define CB_MASK 63
#define CAP_C 3072     // mean 2048/bucket, sigma~45 -> 22-sigma headroom
#define CHUNK 8192     // edges per scatter block (8 per thread)
#define CNT_STRIDE 32  // one counter per 128B

#if __has_builtin(__builtin_amdgcn_exp2f)
#define EXP2(x) __builtin_amdgcn_exp2f(x)
#else
#define EXP2(x) __expf((x)*0.6931471805599453f)
#endif

// Native LDS fp32 atomic add (ds_add_f32); plain atomicAdd would CAS-loop.
__device__ __forceinline__ void lds_fadd(float* p, float v) {
  unsafeAtomicAdd(p, v);
}

// 8-lane-group sum via DPP: quad_perm swap1, swap2, row_half_mirror.
__device__ __forceinline__ float dpp_add_xor1(float x) {
  int v = __builtin_amdgcn_update_dpp(0, __float_as_int(x), 0xB1, 0xF, 0xF, true);
  return x + __int_as_float(v);
}
__device__ __forceinline__ float dpp_add_xor2(float x) {
  int v = __builtin_amdgcn_update_dpp(0, __float_as_int(x), 0x4E, 0xF, 0xF, true);
  return x + __int_as_float(v);
}
__device__ __forceinline__ float dpp_add_half_mirror(float x) {
  int v = __builtin_amdgcn_update_dpp(0, __float_as_int(x), 0x141, 0xF, 0xF, true);
  return x + __int_as_float(v);
}
__device__ __forceinline__ float head8_sum(float x) {
  return dpp_add_half_mirror(dpp_add_xor2(dpp_add_xor1(x)));
}

// out[n][j] = sum_k x[n][k] * W[k][j].  One wave per node per iteration;
// lane j holds W[:,j] in 128 VGPRs; x-row broadcast via readlane.
__global__ __launch_bounds__(256) void gemm_reg(
    const float* __restrict__ x, const float* __restrict__ W,
    float* __restrict__ out, int N, int nwaves) {
  int wid = blockIdx.x * 4 + (threadIdx.x >> 6);
  int j = threadIdx.x & 63;
  float Wcol[128];
#pragma unroll
  for (int k = 0; k < 128; ++k) Wcol[k] = W[k * 64 + j];  // coalesced, L2-hot
  for (int n = wid; n < N; n += nwaves) {
    const float2 xv2 = *(const float2*)&x[(size_t)n * 128 + 2 * j];
    float xa = xv2.x, xb = xv2.y;  // lane l holds x[n][2l], x[n][2l+1]
    float acc0 = 0.f, acc1 = 0.f;
#pragma unroll
    for (int k = 0; k < 128; k += 2) {
      unsigned b0 = __builtin_amdgcn_readlane(__float_as_uint(xa), k >> 1);
      unsigned b1 = __builtin_amdgcn_readlane(__float_as_uint(xb), k >> 1);
      acc0 = fmaf(__uint_as_float(b0), Wcol[k], acc0);
      acc1 = fmaf(__uint_as_float(b1), Wcol[k + 1], acc1);
    }
    out[(size_t)n * 64 + j] = acc0 + acc1;
  }
}

// Block-level counting-sort scatter: CHUNK edges -> bucket-grouped global buf.
__global__ __launch_bounds__(1024) void bucket_scatter(
    const int* __restrict__ ei, int E0, int* __restrict__ bcnt,
    int* __restrict__ buf) {
  __shared__ int hist[1024];          // per-bucket counts (782 used)
  __shared__ int sc[1024];            // scan / later: exclusive seg start
  __shared__ int gofs[1024];          // bucket_base + global_rank - seg_start
  __shared__ unsigned stage[CHUNK];   // (bucket<<22) | entry, bucket-grouped
  int tid = threadIdx.x;
  int base = blockIdx.x * CHUNK;
  hist[tid] = 0;
  __syncthreads();
  int bb[8], pp[8], ent[8];
#pragma unroll
  for (int r = 0; r < 8; ++r) {
    int e = base + r * 1024 + tid;
    if (e < E0) {
      int s = ei[e], d = ei[E0 + e];
      int b = d >> CB_SHIFT;
      bb[r] = b;
      ent[r] = (s << CB_SHIFT) | (d & CB_MASK);
      pp[r] = atomicAdd(&hist[b], 1);  // int LDS atomic: native, fine
    } else {
      bb[r] = -1;
    }
  }
  __syncthreads();
  int v = hist[tid];
  sc[tid] = v;
  __syncthreads();
  for (int off = 1; off < 1024; off <<= 1) {  // Hillis-Steele inclusive scan
    int u = (tid >= off) ? sc[tid - off] : 0;
    __syncthreads();
    sc[tid] += u;
    __syncthreads();
  }
  int total = sc[1023];
  int excl = sc[tid] - v;
  int gb = 0;
  if (v > 0) gb = atomicAdd(&bcnt[tid * CNT_STRIDE], v);  // reserve range
  __syncthreads();
  sc[tid] = excl;                        // seg start of bucket `tid` in stage[]
  gofs[tid] = tid * CAP_C + gb - excl;   // write addr = gofs[bucket] + stage_idx
  __syncthreads();
#pragma unroll
  for (int r = 0; r < 8; ++r) {
    if (bb[r] >= 0)
      stage[sc[bb[r]] + pp[r]] = ((unsigned)bb[r] << 22) | (unsigned)ent[r];
  }
  __syncthreads();
  for (int i = tid; i < total; i += 1024) {
    unsigned pe = stage[i];
    int b = pe >> 22;
    int addr = gofs[b] + i;
    if (addr < b * CAP_C + CAP_C)  // statistical overflow guard (22 sigma)
      buf[addr] = (int)(pe & 0x3FFFFFu);
  }
}

// Fused layer-1 gather: one block per 64-node bucket; LDS accumulators.
__global__ __launch_bounds__(1024) void gather1(
    const int* __restrict__ bcnt, const int* __restrict__ buf,
    const float* __restrict__ xl, const float* __restrict__ xr,
    const float* __restrict__ att, const float* __restrict__ b1,
    const float* __restrict__ W2l, const float* __restrict__ W2r,
    float* __restrict__ hl, float* __restrict__ hr, int N) {
  __shared__ float xrs[64][64];   // xr rows of the bucket's nodes
  __shared__ float accs[64][64];  // sum of w*xl per node
  __shared__ float dens[64][8];   // sum of w per node per head
  int bucket = blockIdx.x;
  int tid = threadIdx.x;
  int w = tid >> 6, lane = tid & 63;
  int cnt = min(bcnt[bucket * CNT_STRIDE], CAP_C);
  int nbase = bucket << CB_SHIFT;
  float av = att[lane] * LOG2E;  // exp(p) == exp2(p*log2e)
  // stage xr rows (coalesced); zero rows past N (never referenced by edges)
  for (int r = w; r < 64; r += 16) {
    int nn = nbase + r;
    xrs[r][lane] = (nn < N) ? xr[(size_t)nn * 64 + lane] : 0.f;
  }
  // self-loop init: wave w inits nodes w*4 .. w*4+3
#pragma unroll
  for (int j = 0; j < 4; ++j) {
    int r = w * 4 + j;
    int nn = nbase + r;
    if (nn < N) {
      float a = xl[(size_t)nn * 64 + lane];
      float bvv = xr[(size_t)nn * 64 + lane];
      float t = a + bvv;
      t = fmaxf(t, NEG_SLOPE * t);
      float wgt = EXP2(head8_sum(t * av));
      accs[r][lane] = wgt * a;
      if ((lane & 7) == 0) dens[r][lane >> 3] = wgt;
    } else {
      accs[r][lane] = 0.f;
      if ((lane & 7) == 0) dens[r][lane >> 3] = 1.f;
    }
  }
  __syncthreads();
  const int* __restrict__ bseg = buf + (size_t)bucket * CAP_C;
  for (int start = w * 64; start < cnt; start += 1024) {
    int rem = cnt - start;
    int e = (start + lane < cnt) ? bseg[start + lane] : 0;
    if (rem >= 64) {
#pragma unroll 8
      for (int i = 0; i < 64; ++i) {
        int ev = __builtin_amdgcn_readlane(e, i);
        int s = ev >> CB_SHIFT, dl = ev & CB_MASK;
        float a = xl[((size_t)s << 6) + lane];
        float t = a + xrs[dl][lane];
        t = fmaxf(t, NEG_SLOPE * t);
        float wgt = EXP2(head8_sum(t * av));
        lds_fadd(&accs[dl][lane], wgt * a);
        if ((lane & 7) == 0) lds_fadd(&dens[dl][lane >> 3], wgt);
      }
    } else {
      for (int i = 0; i < rem; ++i) {
        int ev = __builtin_amdgcn_readlane(e, i);
        int s = ev >> CB_SHIFT, dl = ev & CB_MASK;
        float a = xl[((size_t)s << 6) + lane];
        float t = a + xrs[dl][lane];
        t = fmaxf(t, NEG_SLOPE * t);
        float wgt = EXP2(head8_sum(t * av));
        lds_fadd(&accs[dl][lane], wgt * a);
        if ((lane & 7) == 0) lds_fadd(&dens[dl][lane >> 3], wgt);
      }
    }
  }
  __syncthreads();
  // finalize: normalize, +b1, ELU, project to layer-2 scalars hl, hr
#pragma unroll
  for (int j = 0; j < 4; ++j) {
    int r = w * 4 + j;
    int nn = nbase + r;
    if (nn >= N) continue;
    float v = accs[r][lane] / dens[r][lane >> 3] + b1[lane];
    float h = v > 0.f ? v : (__expf(v) - 1.f);  // ELU(alpha=1)
    float pl = h * W2l[lane];
    float pr = h * W2r[lane];
#pragma unroll
    for (int off = 1; off < 64; off <<= 1) {
      pl += __shfl_xor(pl, off);
      pr += __shfl_xor(pr, off);
    }
    if (lane == 0) { hl[nn] = pl; hr[nn] = pr; }
  }
}

// Layer-2 gather: one block per bucket, fully edge-parallel (one entry per
// thread); LDS num/den per node. hl is 200KB -> L2-resident random gathers.
__global__ __launch_bounds__(1024) void gather2(
    const int* __restrict__ bcnt, const int* __restrict__ buf,
    const float* __restrict__ hl, const float* __restrict__ hr,
    const float* __restrict__ att2, const float* __restrict__ b2,
    float* __restrict__ out, int N) {
  __shared__ float hrs[64];
  __shared__ float num[64];
  __shared__ float den[64];
  int bucket = blockIdx.x;
  int tid = threadIdx.x;
  int cnt = min(bcnt[bucket * CNT_STRIDE], CAP_C);
  int nbase = bucket << CB_SHIFT;
  float a2 = att2[0] * LOG2E;
  if (tid < 64) {  // stage hr + self-loop init
    int nn = nbase + tid;
    if (nn < N) {
      float hld = hl[nn], hrd = hr[nn];
      hrs[tid] = hrd;
      float t = hld + hrd;
      t = fmaxf(t, NEG_SLOPE * t);
      float wgt = EXP2(t * a2);
      num[tid] = wgt * hld;
      den[tid] = wgt;
    } else {
      hrs[tid] = 0.f; num[tid] = 0.f; den[tid] = 1.f;
    }
  }
  __syncthreads();
  const int* __restrict__ bseg = buf + (size_t)bucket * CAP_C;
  for (int i = tid; i < cnt; i += 1024) {
    int e = bseg[i];
    int s = e >> CB_SHIFT, dl = e & CB_MASK;
    float hls = hl[s];
    float t = hls + hrs[dl];
    t = fmaxf(t, NEG_SLOPE * t);
    float wgt = EXP2(t * a2);
    lds_fadd(&num[dl], wgt * hls);
    lds_fadd(&den[dl], wgt);
  }
  __syncthreads();
  if (tid < 64) {
    int nn = nbase + tid;
    if (nn < N) out[nn] = num[tid] / den[tid] + b2[0];
  }
}

extern "C" void kernel_launch(void* const* d_in, const int* in_sizes, int n_in,
                              void* d_out, int out_size, void* d_ws, size_t ws_size,
                              hipStream_t stream) {
  const float* x    = (const float*)d_in[0];
  const int*   ei   = (const int*)d_in[1];
  const float* W1l  = (const float*)d_in[2];
  const float* W1r  = (const float*)d_in[3];
  const float* att1 = (const float*)d_in[4];
  const float* b1   = (const float*)d_in[5];
  const float* W2l  = (const float*)d_in[6];
  const float* W2r  = (const float*)d_in[7];
  const float* att2 = (const float*)d_in[8];
  const float* b2   = (const float*)d_in[9];
  float* out = (float*)d_out;

  const int N  = in_sizes[0] / 128;          // 50000
  const int E0 = in_sizes[1] / 2;            // 1600000
  const int NB = (N + CB_MASK) >> CB_SHIFT;  // 782 buckets of 64 nodes

  // workspace layout
  float* ws  = (float*)d_ws;
  size_t NF  = (size_t)N * 64;
  float* xl  = ws;            // N*64
  float* xr  = xl + NF;       // N*64
  float* hl  = xr + NF;       // N
  float* hr  = hl + N;        // N
  int* bcnt  = (int*)(hr + N);                  // NB*CNT_STRIDE (zeroed)
  int* buf   = bcnt + (size_t)NB * CNT_STRIDE;  // NB*CAP_C

  hipMemsetAsync(bcnt, 0, (size_t)NB * CNT_STRIDE * sizeof(int), stream);

  const int GEMM_BLOCKS = 512;  // 2048 waves
  const int GEMM_WAVES  = GEMM_BLOCKS * 4;
  gemm_reg<<<GEMM_BLOCKS, 256, 0, stream>>>(x, W1l, xl, N, GEMM_WAVES);
  gemm_reg<<<GEMM_BLOCKS, 256, 0, stream>>>(x, W1r, xr, N, GEMM_WAVES);
  bucket_scatter<<<(E0 + CHUNK - 1) / CHUNK, 1024, 0, stream>>>(ei, E0, bcnt, buf);
  gather1<<<NB, 1024, 0, stream>>>(bcnt, buf, xl, xr, att1, b1, W2l, W2r,
                                   hl, hr, N);
  gather2<<<NB, 1024, 0, stream>>>(bcnt, buf, hl, hr, att2, b2, out, N);
}

// Round 10
// 185.281 us; speedup vs baseline: 4.7376x; 4.7296x over previous
//
#include <hip/hip_runtime.h>

// ---------------------------------------------------------------------------
// GATv2 (2 layers), bucket + in-block dst-sort formulation.
// Bucket = dst >> 6 (64 nodes/bucket, 782 buckets). Scatter = block-level
// counting sort into bucket-grouped global buf (coalesced full lines).
// gather1: ONE block per bucket. In-block counting sort by dst (int LDS
// histogram+rank -> 64-bin shfl scan -> placement) gives each node a
// contiguous segment of ents2; wave w then accumulates its 4 nodes'
// segments in REGISTERS (2-deep gather pipeline). Zero fp atomics.
// (R8/R9 lesson: per-edge LDS fp-atomic wave-ops cost ~150cyc each and
//  serialize block-wide -> 788us. Int hist atomics are cheap; fp never.)
// gather2: edge-parallel with 2 scalar LDS fp atomics per THREAD per entry
// (only ~4 atomic wave-ops per wave total -- negligible).
// 8-lane head reduction via DPP; exp2 with log2e prefolded. Softmax without
// max-subtraction (scores O(10), exp fp32-safe; shift-invariant). Self-loops
// handled analytically, never stored.
// ---------------------------------------------------------------------------

#define NEG_SLOPE 0.2f
#define LOG2E 1.4426950408889634f
#define CB_SHIFT 6
#define CB_MASK 63
#define CAP_C 3072     // mean 2048/bucket, sigma~45 -> 22-sigma headroom
#define CHUNK 8192     // edges per scatter block (8 per thread)
#define CNT_STRIDE 32  // one counter per 128B

#if __has_builtin(__builtin_amdgcn_exp2f)
#define EXP2(x) __builtin_amdgcn_exp2f(x)
#else
#define EXP2(x) __expf((x)*0.6931471805599453f)
#endif

__device__ __forceinline__ void lds_fadd(float* p, float v) {
  unsafeAtomicAdd(p, v);
}

// 8-lane-group sum via DPP: quad_perm swap1, swap2, row_half_mirror.
__device__ __forceinline__ float dpp_add_xor1(float x) {
  int v = __builtin_amdgcn_update_dpp(0, __float_as_int(x), 0xB1, 0xF, 0xF, true);
  return x + __int_as_float(v);
}
__device__ __forceinline__ float dpp_add_xor2(float x) {
  int v = __builtin_amdgcn_update_dpp(0, __float_as_int(x), 0x4E, 0xF, 0xF, true);
  return x + __int_as_float(v);
}
__device__ __forceinline__ float dpp_add_half_mirror(float x) {
  int v = __builtin_amdgcn_update_dpp(0, __float_as_int(x), 0x141, 0xF, 0xF, true);
  return x + __int_as_float(v);
}
__device__ __forceinline__ float head8_sum(float x) {
  return dpp_add_half_mirror(dpp_add_xor2(dpp_add_xor1(x)));
}

// out[n][j] = sum_k x[n][k] * W[k][j].  One wave per node per iteration;
// lane j holds W[:,j] in 128 VGPRs; x-row broadcast via readlane.
__global__ __launch_bounds__(256) void gemm_reg(
    const float* __restrict__ x, const float* __restrict__ W,
    float* __restrict__ out, int N, int nwaves) {
  int wid = blockIdx.x * 4 + (threadIdx.x >> 6);
  int j = threadIdx.x & 63;
  float Wcol[128];
#pragma unroll
  for (int k = 0; k < 128; ++k) Wcol[k] = W[k * 64 + j];  // coalesced, L2-hot
  for (int n = wid; n < N; n += nwaves) {
    const float2 xv2 = *(const float2*)&x[(size_t)n * 128 + 2 * j];
    float xa = xv2.x, xb = xv2.y;  // lane l holds x[n][2l], x[n][2l+1]
    float acc0 = 0.f, acc1 = 0.f;
#pragma unroll
    for (int k = 0; k < 128; k += 2) {
      unsigned b0 = __builtin_amdgcn_readlane(__float_as_uint(xa), k >> 1);
      unsigned b1 = __builtin_amdgcn_readlane(__float_as_uint(xb), k >> 1);
      acc0 = fmaf(__uint_as_float(b0), Wcol[k], acc0);
      acc1 = fmaf(__uint_as_float(b1), Wcol[k + 1], acc1);
    }
    out[(size_t)n * 64 + j] = acc0 + acc1;
  }
}

// Block-level counting-sort scatter: CHUNK edges -> bucket-grouped global buf.
__global__ __launch_bounds__(1024) void bucket_scatter(
    const int* __restrict__ ei, int E0, int* __restrict__ bcnt,
    int* __restrict__ buf) {
  __shared__ int hist[1024];          // per-bucket counts (782 used)
  __shared__ int sc[1024];            // scan / later: exclusive seg start
  __shared__ int gofs[1024];          // bucket_base + global_rank - seg_start
  __shared__ unsigned stage[CHUNK];   // (bucket<<22) | entry, bucket-grouped
  int tid = threadIdx.x;
  int base = blockIdx.x * CHUNK;
  hist[tid] = 0;
  __syncthreads();
  int bb[8], pp[8], ent[8];
#pragma unroll
  for (int r = 0; r < 8; ++r) {
    int e = base + r * 1024 + tid;
    if (e < E0) {
      int s = ei[e], d = ei[E0 + e];
      int b = d >> CB_SHIFT;
      bb[r] = b;
      ent[r] = (s << CB_SHIFT) | (d & CB_MASK);
      pp[r] = atomicAdd(&hist[b], 1);  // int LDS atomic: native, fast
    } else {
      bb[r] = -1;
    }
  }
  __syncthreads();
  int v = hist[tid];
  sc[tid] = v;
  __syncthreads();
  for (int off = 1; off < 1024; off <<= 1) {  // Hillis-Steele inclusive scan
    int u = (tid >= off) ? sc[tid - off] : 0;
    __syncthreads();
    sc[tid] += u;
    __syncthreads();
  }
  int total = sc[1023];
  int excl = sc[tid] - v;
  int gb = 0;
  if (v > 0) gb = atomicAdd(&bcnt[tid * CNT_STRIDE], v);  // reserve range
  __syncthreads();
  sc[tid] = excl;                        // seg start of bucket `tid` in stage[]
  gofs[tid] = tid * CAP_C + gb - excl;   // write addr = gofs[bucket] + stage_idx
  __syncthreads();
#pragma unroll
  for (int r = 0; r < 8; ++r) {
    if (bb[r] >= 0)
      stage[sc[bb[r]] + pp[r]] = ((unsigned)bb[r] << 22) | (unsigned)ent[r];
  }
  __syncthreads();
  for (int i = tid; i < total; i += 1024) {
    unsigned pe = stage[i];
    int b = pe >> 22;
    int addr = gofs[b] + i;
    if (addr < b * CAP_C + CAP_C)  // statistical overflow guard (22 sigma)
      buf[addr] = (int)(pe & 0x3FFFFFu);
  }
}

// Fused layer-1 gather: one block per 64-node bucket. In-block dst-sort,
// then per-node segments accumulated in registers (no fp atomics).
__global__ __launch_bounds__(1024) void gather1(
    const int* __restrict__ bcnt, const int* __restrict__ buf,
    const float* __restrict__ xl, const float* __restrict__ xr,
    const float* __restrict__ att, const float* __restrict__ b1,
    const float* __restrict__ W2l, const float* __restrict__ W2r,
    float* __restrict__ hl, float* __restrict__ hr, int N) {
  __shared__ int hist[64];   // per-node edge counts
  __shared__ int ofs[64];    // per-node segment start
  __shared__ int ents2[CAP_C];  // src ids, dst-sorted
  int bucket = blockIdx.x;
  int tid = threadIdx.x;
  int w = tid >> 6, lane = tid & 63;
  int cnt = min(bcnt[bucket * CNT_STRIDE], CAP_C);
  if (tid < 64) hist[tid] = 0;
  __syncthreads();
  // phase 1: read entries (coalesced), rank within dst node (static slots)
  const int* __restrict__ bseg = buf + (size_t)bucket * CAP_C;
  int i0 = tid, i1 = tid + 1024, i2 = tid + 2048;
  int s0v = 0, s1v = 0, s2v = 0, d0v = 0, d1v = 0, d2v = 0;
  int r0v = 0, r1v = 0, r2v = 0;
  bool h0 = i0 < cnt, h1 = i1 < cnt, h2 = i2 < cnt;
  if (h0) { int e = bseg[i0]; d0v = e & CB_MASK; s0v = e >> CB_SHIFT;
            r0v = atomicAdd(&hist[d0v], 1); }
  if (h1) { int e = bseg[i1]; d1v = e & CB_MASK; s1v = e >> CB_SHIFT;
            r1v = atomicAdd(&hist[d1v], 1); }
  if (h2) { int e = bseg[i2]; d2v = e & CB_MASK; s2v = e >> CB_SHIFT;
            r2v = atomicAdd(&hist[d2v], 1); }
  __syncthreads();
  // phase 2: exclusive scan of hist (first wave, shfl)
  if (tid < 64) {
    int v = hist[tid];
    int inc = v;
#pragma unroll
    for (int off = 1; off < 64; off <<= 1) {
      int u = __shfl_up(inc, off);
      if (lane >= off) inc += u;
    }
    ofs[tid] = inc - v;
  }
  __syncthreads();
  // phase 3: place srcs into dst-sorted ents2
  if (h0) ents2[ofs[d0v] + r0v] = s0v;
  if (h1) ents2[ofs[d1v] + r1v] = s1v;
  if (h2) ents2[ofs[d2v] + r2v] = s2v;
  __syncthreads();
  // phase 4: wave w accumulates nodes 4w..4w+3 in registers
  int nbase = bucket << CB_SHIFT;
  float av = att[lane] * LOG2E;  // exp(p) == exp2(p*log2e)
  float b1v = b1[lane], w2lv = W2l[lane], w2rv = W2r[lane];
#pragma unroll
  for (int r4 = 0; r4 < 4; ++r4) {
    int r = (w << 2) | r4;
    int nn = nbase + r;
    if (nn >= N) continue;  // wave-uniform branch
    float bv = xr[((size_t)nn << 6) + lane];
    float acc, den;
    {  // self loop
      float a = xl[((size_t)nn << 6) + lane];
      float t = a + bv; t = fmaxf(t, NEG_SLOPE * t);
      float wgt = EXP2(head8_sum(t * av));
      acc = wgt * a; den = wgt;
    }
    int beg = ofs[r], end = beg + hist[r];
    int j = beg;
    for (; j + 1 < end; j += 2) {  // 2-deep gather pipeline
      int s0 = __builtin_amdgcn_readfirstlane(ents2[j]);
      int s1 = __builtin_amdgcn_readfirstlane(ents2[j + 1]);
      float a0 = xl[((size_t)s0 << 6) + lane];
      float a1 = xl[((size_t)s1 << 6) + lane];
      float t0 = a0 + bv; t0 = fmaxf(t0, NEG_SLOPE * t0);
      float t1 = a1 + bv; t1 = fmaxf(t1, NEG_SLOPE * t1);
      float w0 = EXP2(head8_sum(t0 * av));
      float w1 = EXP2(head8_sum(t1 * av));
      acc = fmaf(w0, a0, acc); den += w0;
      acc = fmaf(w1, a1, acc); den += w1;
    }
    if (j < end) {
      int s0 = __builtin_amdgcn_readfirstlane(ents2[j]);
      float a0 = xl[((size_t)s0 << 6) + lane];
      float t0 = a0 + bv; t0 = fmaxf(t0, NEG_SLOPE * t0);
      float w0 = EXP2(head8_sum(t0 * av));
      acc = fmaf(w0, a0, acc); den += w0;
    }
    // normalize, +b1, ELU, project to layer-2 scalars
    float v = acc / den + b1v;
    float h = v > 0.f ? v : (__expf(v) - 1.f);  // ELU(alpha=1)
    float pl = h * w2lv;
    float pr = h * w2rv;
#pragma unroll
    for (int off = 1; off < 64; off <<= 1) {
      pl += __shfl_xor(pl, off);
      pr += __shfl_xor(pr, off);
    }
    if (lane == 0) { hl[nn] = pl; hr[nn] = pr; }
  }
}

// Layer-2 gather: one block per bucket, edge-parallel (one entry per thread);
// LDS num/den per node (few atomic wave-ops total; hl/hr are L2-resident).
__global__ __launch_bounds__(1024) void gather2(
    const int* __restrict__ bcnt, const int* __restrict__ buf,
    const float* __restrict__ hl, const float* __restrict__ hr,
    const float* __restrict__ att2, const float* __restrict__ b2,
    float* __restrict__ out, int N) {
  __shared__ float hrs[64];
  __shared__ float num[64];
  __shared__ float den[64];
  int bucket = blockIdx.x;
  int tid = threadIdx.x;
  int cnt = min(bcnt[bucket * CNT_STRIDE], CAP_C);
  int nbase = bucket << CB_SHIFT;
  float a2 = att2[0] * LOG2E;
  if (tid < 64) {  // stage hr + self-loop init
    int nn = nbase + tid;
    if (nn < N) {
      float hld = hl[nn], hrd = hr[nn];
      hrs[tid] = hrd;
      float t = hld + hrd;
      t = fmaxf(t, NEG_SLOPE * t);
      float wgt = EXP2(t * a2);
      num[tid] = wgt * hld;
      den[tid] = wgt;
    } else {
      hrs[tid] = 0.f; num[tid] = 0.f; den[tid] = 1.f;
    }
  }
  __syncthreads();
  const int* __restrict__ bseg = buf + (size_t)bucket * CAP_C;
  for (int i = tid; i < cnt; i += 1024) {
    int e = bseg[i];
    int s = e >> CB_SHIFT, dl = e & CB_MASK;
    float hls = hl[s];
    float t = hls + hrs[dl];
    t = fmaxf(t, NEG_SLOPE * t);
    float wgt = EXP2(t * a2);
    lds_fadd(&num[dl], wgt * hls);
    lds_fadd(&den[dl], wgt);
  }
  __syncthreads();
  if (tid < 64) {
    int nn = nbase + tid;
    if (nn < N) out[nn] = num[tid] / den[tid] + b2[0];
  }
}

extern "C" void kernel_launch(void* const* d_in, const int* in_sizes, int n_in,
                              void* d_out, int out_size, void* d_ws, size_t ws_size,
                              hipStream_t stream) {
  const float* x    = (const float*)d_in[0];
  const int*   ei   = (const int*)d_in[1];
  const float* W1l  = (const float*)d_in[2];
  const float* W1r  = (const float*)d_in[3];
  const float* att1 = (const float*)d_in[4];
  const float* b1   = (const float*)d_in[5];
  const float* W2l  = (const float*)d_in[6];
  const float* W2r  = (const float*)d_in[7];
  const float* att2 = (const float*)d_in[8];
  const float* b2   = (const float*)d_in[9];
  float* out = (float*)d_out;

  const int N  = in_sizes[0] / 128;          // 50000
  const int E0 = in_sizes[1] / 2;            // 1600000
  const int NB = (N + CB_MASK) >> CB_SHIFT;  // 782 buckets of 64 nodes

  // workspace layout
  float* ws  = (float*)d_ws;
  size_t NF  = (size_t)N * 64;
  float* xl  = ws;            // N*64
  float* xr  = xl + NF;       // N*64
  float* hl  = xr + NF;       // N
  float* hr  = hl + N;        // N
  int* bcnt  = (int*)(hr + N);                  // NB*CNT_STRIDE (zeroed)
  int* buf   = bcnt + (size_t)NB * CNT_STRIDE;  // NB*CAP_C

  hipMemsetAsync(bcnt, 0, (size_t)NB * CNT_STRIDE * sizeof(int), stream);

  const int GEMM_BLOCKS = 512;  // 2048 waves
  const int GEMM_WAVES  = GEMM_BLOCKS * 4;
  gemm_reg<<<GEMM_BLOCKS, 256, 0, stream>>>(x, W1l, xl, N, GEMM_WAVES);
  gemm_reg<<<GEMM_BLOCKS, 256, 0, stream>>>(x, W1r, xr, N, GEMM_WAVES);
  bucket_scatter<<<(E0 + CHUNK - 1) / CHUNK, 1024, 0, stream>>>(ei, E0, bcnt, buf);
  gather1<<<NB, 1024, 0, stream>>>(bcnt, buf, xl, xr, att1, b1, W2l, W2r,
                                   hl, hr, N);
  gather2<<<NB, 1024, 0, stream>>>(bcnt, buf, hl, hr, att2, b2, out, N);
}